// Round 3
// baseline (1049.415 us; speedup 1.0000x reference)
//
#include <hip/hip_runtime.h>
#include <cstdint>
#include <cstddef>

// ---------------------------------------------------------------------------
// OppoModelNet: fully-fused per-graph forward (R3 mega-fusion).
// Graphs are 128-node blocks; edges are graph-local => one workgroup runs the
// whole network for one graph with activations resident in a 128KB LDS pool.
// Weights: bf16 (pre-converted), streamed from L2 as B-frags (no staging).
// GEMMs: MFMA 16x16x32 bf16, 8 waves (2 row x 4 col), wave tile 64x32/128-tile.
// LDS pool aliasing (u16 elems):
//   [0,32768)      X(TF256) -> NF(TF128)@[0,16K) -> nf2(TF128)
//   [16384,32768)  P_half(RM) -> AGG(TF128)
//   [32768,65536)  ychunk(TF128)@[32K,49K) -> RB(TF256) -> Q(RM)@[32K,49K)
//                  + Hsum(TF128)@[49K,65K) -> hidn(TF256) -> rh(TF256)
// TF layout (frag-friendly): elem(r,k) = (r>>4)*G + (k>>3)*128 + (r&15)*8 + (k&7)
//   G = 4096 (256-wide) or 2048 (128-wide)
// ---------------------------------------------------------------------------

#define NN 65536
#define NE 524288

typedef __bf16 bf16x8 __attribute__((ext_vector_type(8)));
typedef float  f32x4  __attribute__((ext_vector_type(4)));

__device__ __forceinline__ float bf2f(unsigned short u){
  union { unsigned int i; float f; } v; v.i = ((unsigned int)u) << 16; return v.f;
}
__device__ __forceinline__ unsigned short f2b(float f){
  union { float f; unsigned int i; } v; v.f = f;
  unsigned int r = v.i + 0x7FFFu + ((v.i >> 16) & 1u);
  return (unsigned short)(r >> 16);
}
__device__ __forceinline__ float sigm(float x){ return 1.f/(1.f+__expf(-x)); }

// ---------------------------------------------------------------------------
// batched fp32 -> bf16 conversion (weights + obs + h0)
// ---------------------------------------------------------------------------
struct ConvArgs {
  const float* s[14];
  unsigned short* d[14];
  int n4[14];
  int cnt;
};

__global__ __launch_bounds__(256) void convert_kernel(ConvArgs a){
  int stride = gridDim.x * blockDim.x;
  int gid = blockIdx.x * blockDim.x + threadIdx.x;
  for (int seg = 0; seg < a.cnt; ++seg){
    const float4* s = (const float4*)a.s[seg];
    ushort4* d = (ushort4*)a.d[seg];
    int n4 = a.n4[seg];
    for (int i = gid; i < n4; i += stride){
      float4 v = s[i];
      ushort4 o; o.x=f2b(v.x); o.y=f2b(v.y); o.z=f2b(v.z); o.w=f2b(v.w);
      d[i] = o;
    }
  }
}

// ---------------------------------------------------------------------------
// counting sort by dst: hist -> scan -> scatter
// ---------------------------------------------------------------------------
__global__ __launch_bounds__(256) void hist_kernel(
    const int* __restrict__ dst, int* __restrict__ hist)
{
  int e = blockIdx.x * 256 + threadIdx.x;
  atomicAdd(&hist[dst[e]], 1);
}

__global__ __launch_bounds__(256) void scan1_kernel(
    const int* __restrict__ hist, int* __restrict__ offs, int* __restrict__ bsum)
{
  __shared__ int s[256];
  int b = blockIdx.x, t = threadIdx.x;
  int v = hist[b * 256 + t];
  s[t] = v; __syncthreads();
  for (int d = 1; d < 256; d <<= 1){
    int x = (t >= d) ? s[t - d] : 0;
    __syncthreads();
    s[t] += x;
    __syncthreads();
  }
  offs[b * 256 + t] = s[t] - v;
  if (t == 255) bsum[b] = s[255];
}

__global__ __launch_bounds__(256) void scan2_kernel(int* __restrict__ bsum){
  __shared__ int s[256];
  int t = threadIdx.x;
  int v = bsum[t];
  s[t] = v; __syncthreads();
  for (int d = 1; d < 256; d <<= 1){
    int x = (t >= d) ? s[t - d] : 0;
    __syncthreads();
    s[t] += x;
    __syncthreads();
  }
  bsum[t] = s[t] - v;
}

__global__ __launch_bounds__(256) void scan3_kernel(
    int* __restrict__ offs, const int* __restrict__ bsum, int* __restrict__ cursor)
{
  int i = blockIdx.x * 256 + threadIdx.x;
  int v = offs[i] + bsum[blockIdx.x];
  offs[i] = v;
  cursor[i] = v;
}

__global__ __launch_bounds__(256) void scatter_kernel(
    const int* __restrict__ src, const int* __restrict__ dst,
    int* __restrict__ cursor, int* __restrict__ sorted_src)
{
  int e = blockIdx.x * 256 + threadIdx.x;
  int d = dst[e];
  int pos = atomicAdd(&cursor[d], 1);
  sorted_src[pos] = src[e];
}

// ---------------------------------------------------------------------------
// the mega kernel: one block = one 128-node graph, 512 threads = 8 waves (2x4)
// ---------------------------------------------------------------------------
#define POOL_X   0        // TF256 [0,32768)
#define POOL_NF  0        // TF128 [0,16384)
#define POOL_NF2 0        // TF128 [0,16384)
#define POOL_P   16384    // row-major [128][128] [16384,32768)
#define POOL_AGG 16384    // TF128 [16384,32768)
#define POOL_YC  32768    // TF128 [32768,49152)
#define POOL_RB  32768    // TF256 [32768,65536)
#define POOL_Q   32768    // row-major [32768,49152)
#define POOL_HS  49152    // TF128 [49152,65536)
#define POOL_HID 32768    // TF256 [32768,65536)
#define POOL_RH  32768    // TF256 [32768,65536)

__global__ __launch_bounds__(512, 2) void fused_kernel(
    const unsigned short* __restrict__ obs_b,  // [N][256] bf16
    const unsigned short* __restrict__ h0_b,   // [N][256] bf16
    const float* __restrict__ c0,              // [N][256] fp32
    const unsigned short* __restrict__ w1a_b,  // [512][256]
    const float* __restrict__ b1a,
    const unsigned short* __restrict__ w1b_b,  // [256][512]
    const float* __restrict__ b1b,
    const unsigned short* __restrict__ wih_b,  // [1024][256]
    const unsigned short* __restrict__ whh_b,  // [1024][256]
    const float* __restrict__ b_ih, const float* __restrict__ b_hh,
    const unsigned short* __restrict__ w1_b,   // [128][256]
    const float* __restrict__ b1,
    const unsigned short* __restrict__ we_b,   // [256][256]
    const float* __restrict__ be,
    const unsigned short* __restrict__ we2_b,  // [128][256]
    const float* __restrict__ be2,
    const unsigned short* __restrict__ wn_b,   // [256][256]
    const float* __restrict__ bn,
    const unsigned short* __restrict__ wn2_b,  // [128][256]
    const float* __restrict__ bn2,
    const unsigned short* __restrict__ wr_b,   // [256][128]
    const float* __restrict__ br,
    const unsigned short* __restrict__ wr2_b,  // [8][256]
    const float* __restrict__ br2,
    const int* __restrict__ hist, const int* __restrict__ offs,
    const int* __restrict__ ssrc,
    float* __restrict__ logits, float* __restrict__ h1o, float* __restrict__ c1o)
{
  __shared__ alignas(16) unsigned short pool[65536];   // 128 KB

  int tid = threadIdx.x;
  int w = tid >> 6, lane = tid & 63;
  int wr = w >> 2, wc = w & 3;           // 2 x 4 wave grid
  int l15 = lane & 15, l4 = lane >> 4;
  int g = blockIdx.x;
  int gbase = g << 7;

  // --- frag loaders ---
  auto ldA_gb = [&](const unsigned short* base, int rt, int ks) -> bf16x8 {
    return *(const bf16x8*)(base + (size_t)(gbase + (rt << 4) + l15) * 256 + (ks << 5) + (l4 << 3));
  };
  auto ldB = [&](const unsigned short* W, int ldw, int n0, int ks) -> bf16x8 {
    return *(const bf16x8*)(W + (size_t)(n0 + l15) * ldw + (ks << 5) + (l4 << 3));
  };
  auto ldA_tf256 = [&](int base, int rt, int ks) -> bf16x8 {
    return *(const bf16x8*)&pool[base + (rt << 12) + (((ks << 2) + l4) << 7) + (l15 << 3)];
  };
  auto ldA_tf128 = [&](int base, int rt, int ks) -> bf16x8 {
    return *(const bf16x8*)&pool[base + (rt << 11) + (((ks << 2) + l4) << 7) + (l15 << 3)];
  };
  auto stTF256 = [&](int base, int row, int col, unsigned short v){
    pool[base + ((row >> 4) << 12) + ((col >> 3) << 7) + ((row & 15) << 3) + (col & 7)] = v;
  };
  auto stTF128 = [&](int base, int row, int col, unsigned short v){
    pool[base + ((row >> 4) << 11) + ((col >> 3) << 7) + ((row & 15) << 3) + (col & 7)] = v;
  };

  // ===== stage 1+2: y1 = relu(obs@w1a^T+b1a) chunked; x = y1@w1b^T+b1b =====
  {
    f32x4 xacc[2][4][2] = {};
    for (int c = 0; c < 4; ++c){
      f32x4 yacc[4][2] = {};
#pragma unroll
      for (int ks = 0; ks < 8; ++ks){
        bf16x8 a[4];
#pragma unroll
        for (int m = 0; m < 4; ++m) a[m] = ldA_gb(obs_b, (wr << 2) + m, ks);
#pragma unroll
        for (int n = 0; n < 2; ++n){
          bf16x8 b = ldB(w1a_b, 256, c * 128 + (wc << 5) + (n << 4), ks);
#pragma unroll
          for (int m = 0; m < 4; ++m)
            yacc[m][n] = __builtin_amdgcn_mfma_f32_16x16x32_bf16(a[m], b, yacc[m][n], 0, 0, 0);
        }
      }
      // epilogue: relu + b1a -> ychunk (TF128)
#pragma unroll
      for (int n = 0; n < 2; ++n){
        float bv = b1a[c * 128 + (wc << 5) + (n << 4) + l15];
#pragma unroll
        for (int m = 0; m < 4; ++m)
#pragma unroll
          for (int r = 0; r < 4; ++r){
            int row = (wr << 6) + (m << 4) + (l4 << 2) + r;
            int col = (wc << 5) + (n << 4) + l15;
            stTF128(POOL_YC, row, col, f2b(fmaxf(yacc[m][n][r] + bv, 0.f)));
          }
      }
      __syncthreads();
      // x += ychunk @ w1b[:, c*128..]^T
#pragma unroll
      for (int ks = 0; ks < 4; ++ks){
        bf16x8 a[4];
#pragma unroll
        for (int m = 0; m < 4; ++m) a[m] = ldA_tf128(POOL_YC, (wr << 2) + m, ks);
#pragma unroll
        for (int nt = 0; nt < 2; ++nt)
#pragma unroll
          for (int n = 0; n < 2; ++n){
            bf16x8 b = ldB(w1b_b, 512, nt * 128 + (wc << 5) + (n << 4), c * 4 + ks);
#pragma unroll
            for (int m = 0; m < 4; ++m)
              xacc[nt][m][n] = __builtin_amdgcn_mfma_f32_16x16x32_bf16(a[m], b, xacc[nt][m][n], 0, 0, 0);
          }
      }
      __syncthreads();  // before ychunk overwrite
    }
    // x epilogue -> X (TF256)
#pragma unroll
    for (int nt = 0; nt < 2; ++nt)
#pragma unroll
      for (int n = 0; n < 2; ++n){
        int col = nt * 128 + (wc << 5) + (n << 4) + l15;
        float bv = b1b[col];
#pragma unroll
        for (int m = 0; m < 4; ++m)
#pragma unroll
          for (int r = 0; r < 4; ++r){
            int row = (wr << 6) + (m << 4) + (l4 << 2) + r;
            stTF256(POOL_X, row, col, f2b(xacc[nt][m][n][r] + bv));
          }
      }
  }
  __syncthreads();

  // ===== stage 3: gates + LSTM -> h1o, c1o, RB(=relu(h1)) =====
  for (int cc = 0; cc < 2; ++cc){
    f32x4 gacc[4][4][2] = {};   // [gate][m][n]
#pragma unroll
    for (int ks = 0; ks < 16; ++ks){
      bf16x8 a[4];
      const unsigned short* Wb;
      int krel;
      if (ks < 8){
#pragma unroll
        for (int m = 0; m < 4; ++m) a[m] = ldA_tf256(POOL_X, (wr << 2) + m, ks);
        Wb = wih_b; krel = ks;
      } else {
#pragma unroll
        for (int m = 0; m < 4; ++m) a[m] = ldA_gb(h0_b, (wr << 2) + m, ks - 8);
        Wb = whh_b; krel = ks - 8;
      }
#pragma unroll
      for (int gg = 0; gg < 4; ++gg)
#pragma unroll
        for (int n = 0; n < 2; ++n){
          bf16x8 b = ldB(Wb, 256, gg * 256 + cc * 128 + (wc << 5) + (n << 4), krel);
#pragma unroll
          for (int m = 0; m < 4; ++m)
            gacc[gg][m][n] = __builtin_amdgcn_mfma_f32_16x16x32_bf16(a[m], b, gacc[gg][m][n], 0, 0, 0);
        }
    }
    // LSTM epilogue
#pragma unroll
    for (int n = 0; n < 2; ++n){
      int col = cc * 128 + (wc << 5) + (n << 4) + l15;
      float bi  = b_ih[col]       + b_hh[col];
      float bff = b_ih[256 + col] + b_hh[256 + col];
      float bg  = b_ih[512 + col] + b_hh[512 + col];
      float bo  = b_ih[768 + col] + b_hh[768 + col];
#pragma unroll
      for (int m = 0; m < 4; ++m)
#pragma unroll
        for (int r = 0; r < 4; ++r){
          int row = (wr << 6) + (m << 4) + (l4 << 2) + r;
          size_t off = (size_t)(gbase + row) * 256 + col;
          float iv = sigm(gacc[0][m][n][r] + bi);
          float fv = sigm(gacc[1][m][n][r] + bff);
          float gv = tanhf(gacc[2][m][n][r] + bg);
          float ov = sigm(gacc[3][m][n][r] + bo);
          float cv = fv * c0[off] + iv * gv;
          float hv = ov * tanhf(cv);
          h1o[off] = hv;
          c1o[off] = cv;
          stTF256(POOL_RB, row, col, f2b(fmaxf(hv, 0.f)));
        }
    }
  }
  __syncthreads();

  // ===== stage 4: nf = RB @ w1^T + b1 -> NF (TF128) =====
  {
    f32x4 acc[4][2] = {};
#pragma unroll
    for (int ks = 0; ks < 8; ++ks){
      bf16x8 a[4];
#pragma unroll
      for (int m = 0; m < 4; ++m) a[m] = ldA_tf256(POOL_RB, (wr << 2) + m, ks);
#pragma unroll
      for (int n = 0; n < 2; ++n){
        bf16x8 b = ldB(w1_b, 256, (wc << 5) + (n << 4), ks);
#pragma unroll
        for (int m = 0; m < 4; ++m)
          acc[m][n] = __builtin_amdgcn_mfma_f32_16x16x32_bf16(a[m], b, acc[m][n], 0, 0, 0);
      }
    }
#pragma unroll
    for (int n = 0; n < 2; ++n){
      int col = (wc << 5) + (n << 4) + l15;
      float bv = b1[col];
#pragma unroll
      for (int m = 0; m < 4; ++m)
#pragma unroll
        for (int r = 0; r < 4; ++r){
          int row = (wr << 6) + (m << 4) + (l4 << 2) + r;
          stTF128(POOL_NF, row, col, f2b(acc[m][n][r] + bv));
        }
    }
  }
  __syncthreads();

  // ===== stages 5-7: edge MLP halves + aggregation + agg GEMM =====
  f32x4 agg_acc[4][2] = {};
  for (int h = 0; h < 2; ++h){
    {  // P_h = NF@we_L[h]^T ; Q_h = NF@we_R[h]^T + be_h   (row-major out)
      f32x4 pacc[4][2] = {}, qacc[4][2] = {};
#pragma unroll
      for (int ks = 0; ks < 4; ++ks){
        bf16x8 a[4];
#pragma unroll
        for (int m = 0; m < 4; ++m) a[m] = ldA_tf128(POOL_NF, (wr << 2) + m, ks);
#pragma unroll
        for (int n = 0; n < 2; ++n){
          bf16x8 bp = ldB(we_b, 256, h * 128 + (wc << 5) + (n << 4), ks);
          bf16x8 bq = ldB(we_b, 256, h * 128 + (wc << 5) + (n << 4), ks + 4);
#pragma unroll
          for (int m = 0; m < 4; ++m){
            pacc[m][n] = __builtin_amdgcn_mfma_f32_16x16x32_bf16(a[m], bp, pacc[m][n], 0, 0, 0);
            qacc[m][n] = __builtin_amdgcn_mfma_f32_16x16x32_bf16(a[m], bq, qacc[m][n], 0, 0, 0);
          }
        }
      }
#pragma unroll
      for (int n = 0; n < 2; ++n){
        int col = (wc << 5) + (n << 4) + l15;
        float bv = be[h * 128 + col];
#pragma unroll
        for (int m = 0; m < 4; ++m)
#pragma unroll
          for (int r = 0; r < 4; ++r){
            int row = (wr << 6) + (m << 4) + (l4 << 2) + r;
            pool[POOL_P + row * 128 + col] = f2b(pacc[m][n][r]);
            pool[POOL_Q + row * 128 + col] = f2b(qacc[m][n][r] + bv);
          }
      }
    }
    __syncthreads();
    // edge aggregation: Hsum_h[n] = sum relu(P[src]+Q[n]); wave = 2 nodes/pass
    {
      int hl = lane >> 5, ll = lane & 31;
      int d0 = ll << 2;
#pragma unroll 1
      for (int pass = 0; pass < 8; ++pass){
        int ln = (pass << 4) + (w << 1) + hl;
        int ng = gbase + ln;
        int eoff = offs[ng], ecnt = hist[ng];
        unsigned long long qv = *(const unsigned long long*)&pool[POOL_Q + ln * 128 + d0];
        float q0 = bf2f((unsigned short)qv);
        float q1 = bf2f((unsigned short)(qv >> 16));
        float q2 = bf2f((unsigned short)(qv >> 32));
        float q3 = bf2f((unsigned short)(qv >> 48));
        float s0 = 0.f, s1 = 0.f, s2 = 0.f, s3 = 0.f;
        for (int i = 0; i < ecnt; ++i){
          int s = ssrc[eoff + i] - gbase;
          unsigned long long pv = *(const unsigned long long*)&pool[POOL_P + s * 128 + d0];
          s0 += fmaxf(bf2f((unsigned short)pv) + q0, 0.f);
          s1 += fmaxf(bf2f((unsigned short)(pv >> 16)) + q1, 0.f);
          s2 += fmaxf(bf2f((unsigned short)(pv >> 32)) + q2, 0.f);
          s3 += fmaxf(bf2f((unsigned short)(pv >> 48)) + q3, 0.f);
        }
        unsigned long long hv = (unsigned long long)f2b(s0)
                              | ((unsigned long long)f2b(s1) << 16)
                              | ((unsigned long long)f2b(s2) << 32)
                              | ((unsigned long long)f2b(s3) << 48);
        *(unsigned long long*)&pool[POOL_HS + ((ln >> 4) << 11) + ((d0 >> 3) << 7) + ((ln & 15) << 3) + (d0 & 7)] = hv;
      }
    }
    __syncthreads();
    // agg_acc += Hsum_h @ we2[:, h*128..]^T
#pragma unroll
    for (int ks = 0; ks < 4; ++ks){
      bf16x8 a[4];
#pragma unroll
      for (int m = 0; m < 4; ++m) a[m] = ldA_tf128(POOL_HS, (wr << 2) + m, ks);
#pragma unroll
      for (int n = 0; n < 2; ++n){
        bf16x8 b = ldB(we2_b, 256, (wc << 5) + (n << 4), h * 4 + ks);
#pragma unroll
        for (int m = 0; m < 4; ++m)
          agg_acc[m][n] = __builtin_amdgcn_mfma_f32_16x16x32_bf16(a[m], b, agg_acc[m][n], 0, 0, 0);
      }
    }
    __syncthreads();  // before next h overwrites P/Q/HS
  }
  // AGG epilogue: + deg*be2 -> TF128 @ POOL_AGG
#pragma unroll
  for (int n = 0; n < 2; ++n){
    int col = (wc << 5) + (n << 4) + l15;
    float bv = be2[col];
#pragma unroll
    for (int m = 0; m < 4; ++m)
#pragma unroll
      for (int r = 0; r < 4; ++r){
        int row = (wr << 6) + (m << 4) + (l4 << 2) + r;
        float dv = (float)hist[gbase + row];
        stTF128(POOL_AGG, row, col, f2b(agg_acc[m][n][r] + bv * dv));
      }
  }
  __syncthreads();

  // ===== stage 8: hidn = relu([NF|AGG] @ wn^T + bn) -> HID (TF256) =====
  {
    f32x4 hacc[2][4][2] = {};
#pragma unroll
    for (int ks = 0; ks < 8; ++ks){
      bf16x8 a[4];
      if (ks < 4){
#pragma unroll
        for (int m = 0; m < 4; ++m) a[m] = ldA_tf128(POOL_NF, (wr << 2) + m, ks);
      } else {
#pragma unroll
        for (int m = 0; m < 4; ++m) a[m] = ldA_tf128(POOL_AGG, (wr << 2) + m, ks - 4);
      }
#pragma unroll
      for (int nt = 0; nt < 2; ++nt)
#pragma unroll
        for (int n = 0; n < 2; ++n){
          bf16x8 b = ldB(wn_b, 256, nt * 128 + (wc << 5) + (n << 4), ks);
#pragma unroll
          for (int m = 0; m < 4; ++m)
            hacc[nt][m][n] = __builtin_amdgcn_mfma_f32_16x16x32_bf16(a[m], b, hacc[nt][m][n], 0, 0, 0);
        }
    }
    __syncthreads();   // all waves done reading NF/AGG & (earlier) HID region free
#pragma unroll
    for (int nt = 0; nt < 2; ++nt)
#pragma unroll
      for (int n = 0; n < 2; ++n){
        int col = nt * 128 + (wc << 5) + (n << 4) + l15;
        float bv = bn[col];
#pragma unroll
        for (int m = 0; m < 4; ++m)
#pragma unroll
          for (int r = 0; r < 4; ++r){
            int row = (wr << 6) + (m << 4) + (l4 << 2) + r;
            stTF256(POOL_HID, row, col, f2b(fmaxf(hacc[nt][m][n][r] + bv, 0.f)));
          }
      }
  }
  __syncthreads();

  // ===== stage 9: nf2 = HID @ wn2^T + bn2 -> NF2 (TF128 @0) =====
  {
    f32x4 acc[4][2] = {};
#pragma unroll
    for (int ks = 0; ks < 8; ++ks){
      bf16x8 a[4];
#pragma unroll
      for (int m = 0; m < 4; ++m) a[m] = ldA_tf256(POOL_HID, (wr << 2) + m, ks);
#pragma unroll
      for (int n = 0; n < 2; ++n){
        bf16x8 b = ldB(wn2_b, 256, (wc << 5) + (n << 4), ks);
#pragma unroll
        for (int m = 0; m < 4; ++m)
          acc[m][n] = __builtin_amdgcn_mfma_f32_16x16x32_bf16(a[m], b, acc[m][n], 0, 0, 0);
      }
    }
    __syncthreads();   // NF free (read in stage 8)
#pragma unroll
    for (int n = 0; n < 2; ++n){
      int col = (wc << 5) + (n << 4) + l15;
      float bv = bn2[col];
#pragma unroll
      for (int m = 0; m < 4; ++m)
#pragma unroll
        for (int r = 0; r < 4; ++r){
          int row = (wr << 6) + (m << 4) + (l4 << 2) + r;
          stTF128(POOL_NF2, row, col, f2b(acc[m][n][r] + bv));
        }
    }
  }
  __syncthreads();

  // ===== stage 10: rh = relu(NF2 @ wr^T + br) -> RH (TF256) =====
  {
    f32x4 racc[2][4][2] = {};
#pragma unroll
    for (int ks = 0; ks < 4; ++ks){
      bf16x8 a[4];
#pragma unroll
      for (int m = 0; m < 4; ++m) a[m] = ldA_tf128(POOL_NF2, (wr << 2) + m, ks);
#pragma unroll
      for (int nt = 0; nt < 2; ++nt)
#pragma unroll
        for (int n = 0; n < 2; ++n){
          bf16x8 b = ldB(wr_b, 128, nt * 128 + (wc << 5) + (n << 4), ks);
#pragma unroll
          for (int m = 0; m < 4; ++m)
            racc[nt][m][n] = __builtin_amdgcn_mfma_f32_16x16x32_bf16(a[m], b, racc[nt][m][n], 0, 0, 0);
        }
    }
    __syncthreads();   // HID free (read in stage 9)
#pragma unroll
    for (int nt = 0; nt < 2; ++nt)
#pragma unroll
      for (int n = 0; n < 2; ++n){
        int col = nt * 128 + (wc << 5) + (n << 4) + l15;
        float bv = br[col];
#pragma unroll
        for (int m = 0; m < 4; ++m)
#pragma unroll
          for (int r = 0; r < 4; ++r){
            int row = (wr << 6) + (m << 4) + (l4 << 2) + r;
            stTF256(POOL_RH, row, col, f2b(fmaxf(racc[nt][m][n][r] + bv, 0.f)));
          }
      }
  }
  __syncthreads();

  // ===== stage 11: logits = RH @ wr2^T + br2 (fp32 out) =====
  {
    int node = tid >> 2, q = tid & 3;
    int o0 = q << 1;
    float s0 = br2[o0], s1 = br2[o0 + 1];
    const unsigned short* w0 = wr2_b + (size_t)o0 * 256;
    const unsigned short* w1 = w0 + 256;
#pragma unroll
    for (int kc = 0; kc < 32; ++kc){
      const unsigned short* rp = &pool[POOL_RH + ((node >> 4) << 12) + (kc << 7) + ((node & 15) << 3)];
      const unsigned short* wp0 = w0 + kc * 8;
      const unsigned short* wp1 = w1 + kc * 8;
#pragma unroll
      for (int i = 0; i < 8; ++i){
        float rv = bf2f(rp[i]);
        s0 += rv * bf2f(wp0[i]);
        s1 += rv * bf2f(wp1[i]);
      }
    }
    size_t ob = (size_t)(gbase + node) * 8 + o0;
    logits[ob] = s0;
    logits[ob + 1] = s1;
  }
}

// ---------------------------------------------------------------------------
extern "C" void kernel_launch(void* const* d_in, const int* in_sizes, int n_in,
                              void* d_out, int out_size, void* d_ws, size_t ws_size,
                              hipStream_t stream)
{
  (void)in_sizes; (void)n_in; (void)out_size; (void)ws_size;
  const float* obs = (const float*)d_in[0];
  const float* h0  = (const float*)d_in[1];
  const float* c0  = (const float*)d_in[2];
  const int*   src = (const int*)d_in[3];
  const int*   dst = (const int*)d_in[4];
  const float* w1a = (const float*)d_in[5];
  const float* b1a = (const float*)d_in[6];
  const float* w1b = (const float*)d_in[7];
  const float* b1b = (const float*)d_in[8];
  const float* wih = (const float*)d_in[9];
  const float* bih = (const float*)d_in[10];
  const float* whh = (const float*)d_in[11];
  const float* bhh = (const float*)d_in[12];
  const float* w1  = (const float*)d_in[13];
  const float* b1  = (const float*)d_in[14];
  const float* we  = (const float*)d_in[15];
  const float* be  = (const float*)d_in[16];
  const float* we2 = (const float*)d_in[17];
  const float* be2 = (const float*)d_in[18];
  const float* wn  = (const float*)d_in[19];
  const float* bn  = (const float*)d_in[20];
  const float* wn2 = (const float*)d_in[21];
  const float* bn2 = (const float*)d_in[22];
  const float* wr  = (const float*)d_in[23];
  const float* br  = (const float*)d_in[24];
  const float* wr2 = (const float*)d_in[25];
  const float* br2 = (const float*)d_in[26];

  char* ws = (char*)d_ws;
  typedef unsigned short u16;
  u16* w1a_b = (u16*)(ws + 0);
  u16* w1b_b = (u16*)(ws + 262144);
  u16* wih_b = (u16*)(ws + 524288);
  u16* whh_b = (u16*)(ws + 1048576);
  u16* w1_b  = (u16*)(ws + 1572864);
  u16* we_b  = (u16*)(ws + 1638400);
  u16* we2_b = (u16*)(ws + 1769472);
  u16* wn_b  = (u16*)(ws + 1835008);
  u16* wn2_b = (u16*)(ws + 1966080);
  u16* wr_b  = (u16*)(ws + 2031616);
  u16* wr2_b = (u16*)(ws + 2097152);
  int* hist    = (int*)(ws + 2103296);          // [65536] = deg
  int* offs    = (int*)(ws + 2365440);          // [65536]
  int* cursor  = (int*)(ws + 2627584);          // [65536]
  int* bsum    = (int*)(ws + 2889728);          // [256]
  int* ssrc    = (int*)(ws + 2890752);          // sorted_src [524288]

  u16* obs_b = (u16*)(ws + 5242880);            // [N][256] bf16
  u16* h0_b  = (u16*)(ws + 38797312);           // [N][256] bf16

  float* logits = (float*)d_out;
  float* h1o = logits + (size_t)NN * 8;
  float* c1o = h1o + (size_t)NN * 256;

  // 0) zero hist
  (void)hipMemsetAsync(hist, 0, 65536 * 4, stream);

  // 1) convert fp32 -> bf16 (weights + obs + h0)
  ConvArgs ca;
  const float* ss[13] = {obs, h0, w1a, w1b, wih, whh, w1, we, we2, wn, wn2, wr, wr2};
  u16* dd[13] = {obs_b, h0_b, w1a_b, w1b_b, wih_b, whh_b, w1_b, we_b, we2_b, wn_b, wn2_b, wr_b, wr2_b};
  int nn[13] = {NN*256, NN*256, 512*256, 256*512, 1024*256, 1024*256, 128*256,
                256*256, 128*256, 256*256, 128*256, 256*128, 8*256};
  for (int i = 0; i < 13; ++i){ ca.s[i]=ss[i]; ca.d[i]=dd[i]; ca.n4[i]=nn[i]/4; }
  ca.cnt = 13;
  convert_kernel<<<2048, 256, 0, stream>>>(ca);

  // 2) counting sort of edges by dst
  hist_kernel<<<NE/256, 256, 0, stream>>>(dst, hist);
  scan1_kernel<<<256, 256, 0, stream>>>(hist, offs, bsum);
  scan2_kernel<<<1, 256, 0, stream>>>(bsum);
  scan3_kernel<<<256, 256, 0, stream>>>(offs, bsum, cursor);
  scatter_kernel<<<NE/256, 256, 0, stream>>>(src, dst, cursor, ssrc);

  // 3) the whole network, one block per graph
  fused_kernel<<<NN/128, 512, 0, stream>>>(
      obs_b, h0_b, c0,
      w1a_b, b1a, w1b_b, b1b,
      wih_b, whh_b, bih, bhh,
      w1_b, b1,
      we_b, be, we2_b, be2,
      wn_b, bn, wn2_b, bn2,
      wr_b, br, wr2_b, br2,
      hist, offs, ssrc,
      logits, h1o, c1o);
}